// Round 19
// baseline (81.746 us; speedup 1.0000x reference)
//
#include <hip/hip_runtime.h>
#include <math.h>

#define NB 8
#define TT 2048
#define DD 1024
#define NTI2 8            // 2048 / 256 t-tiles
#define NPAIR2 36         // NTI2*(NTI2+1)/2

typedef __attribute__((ext_vector_type(4))) int intx4;
typedef __attribute__((ext_vector_type(4))) float floatx4;

__device__ inline float fast_gelu(float x) {
    // tanh(z) = 1 - 2/(exp(2z)+1); __expf -> v_exp_f32
    float z = 0.7978845608028654f * (x + 0.044715f * x * x * x);
    float e = __expf(2.0f * z);
    float th = 1.0f - 2.0f / (e + 1.0f);
    return 0.5f * x * (1.0f + th);
}

// ------- kernel A: gelu + row norm + ema dot -> int8 out_norm, ema_sim -------
__global__ __launch_bounds__(256) void k_gelu_norm(
        const float* __restrict__ x, const float* __restrict__ ema,
        unsigned int* __restrict__ onrm8, float* __restrict__ ema_sim) {
    int row = blockIdx.x * 4 + (threadIdx.x >> 6);
    int lane = threadIdx.x & 63;
    const float4* xr = reinterpret_cast<const float4*>(x + (size_t)row * DD);
    const float4* er = reinterpret_cast<const float4*>(ema);
    float g[16];
    float ss = 0.f, dt = 0.f, e2 = 0.f;
#pragma unroll
    for (int j = 0; j < 4; ++j) {
        float4 v = xr[j * 64 + lane];
        float4 e = er[j * 64 + lane];
        float vv[4] = {v.x, v.y, v.z, v.w};
        float ee[4] = {e.x, e.y, e.z, e.w};
        e2 += ee[0] * ee[0] + ee[1] * ee[1] + ee[2] * ee[2] + ee[3] * ee[3];
#pragma unroll
        for (int i = 0; i < 4; ++i) {
            float o = fast_gelu(vv[i]);
            g[j * 4 + i] = o;
            ss += o * o;
            dt += o * ee[i];
        }
    }
#pragma unroll
    for (int m = 1; m < 64; m <<= 1) {
        ss += __shfl_xor(ss, m);
        dt += __shfl_xor(dt, m);
        e2 += __shfl_xor(e2, m);
    }
    float inv = 1.0f / fmaxf(sqrtf(ss), 1e-12f);
    float einv = 1.0f / fmaxf(sqrtf(e2), 1e-12f);
    unsigned int* o8 = onrm8 + (size_t)row * (DD / 4);
#pragma unroll
    for (int j = 0; j < 4; ++j) {
        int q0 = (int)rintf(g[j * 4 + 0] * inv * 127.0f);
        int q1 = (int)rintf(g[j * 4 + 1] * inv * 127.0f);
        int q2 = (int)rintf(g[j * 4 + 2] * inv * 127.0f);
        int q3 = (int)rintf(g[j * 4 + 3] * inv * 127.0f);
        unsigned pk = (q0 & 255) | ((q1 & 255) << 8) | ((q2 & 255) << 16) |
                      ((unsigned)(q3 & 255) << 24);
        o8[j * 64 + lane] = pk;
    }
    if (lane == 0) ema_sim[row] = dt * inv * einv;
}

// -------- kernel B: causal max similarity, 256x256 int8 MFMA GEMM ------------
// grid = NB*36 lower-tri 256x256 tile pairs; 288 % 8 == 0 and 288/8 = 36 =
// one full batch per XCD (2 MB i8 slice L2-resident; all 36 blocks of an
// XCD co-resident at the 2-blocks/CU LDS cap). 512 threads = 8 waves; wave
// (wr=w&3, wc=w>>2) owns a 64x128 sub-tile = 4x8 frags of
// mfma_i32_16x16x64_i8 (R13's proven 0-conflict ds_read_b128 pattern,
// byte-identical 128B-row swizzle). vs R13's 128² tile: staged bytes/output
// halved (A/B reuse 2x), LDS-read bytes -21% -- attacks the measured
// stage+LDS throughput chain (R17 proved barriers alone are not the cost).
// BK=128 -> 8 K-steps, single-buffer 64 KB LDS, global_load_lds w=16,
// XOR-pre-swizzled source (linear LDS dest), 2 __syncthreads per K-step.
__global__ __launch_bounds__(512) void k_seqmax(const unsigned char* __restrict__ onrm8,
                                                float* __restrict__ part) {
    __shared__ __align__(16) unsigned char lds[65536];   // A @0, B @32768

    int id = blockIdx.x;
    int nid = (id & 7) * NPAIR2 + (id >> 3);     // bijective: 288 % 8 == 0
    int b = nid / NPAIR2;
    int p = nid % NPAIR2;
    int ti = (int)((sqrtf(8.0f * (float)p + 1.0f) - 1.0f) * 0.5f);
    while ((ti + 1) * (ti + 2) / 2 <= p) ++ti;
    while (ti * (ti + 1) / 2 > p) --ti;
    int sj = p - ti * (ti + 1) / 2;

    int tid = threadIdx.x;
    int lane = tid & 63;
    int wave = tid >> 6;                         // 0..7
    int wr = wave & 3, wc = wave >> 2;           // 4 row-bands x 2 col-halves
    int rl = lane & 15, g = lane >> 4;

    const unsigned char* Abase = onrm8 + (size_t)(b * TT + ti * 256) * DD;
    const unsigned char* Bbase = onrm8 + (size_t)(b * TT + sj * 256) * DD;

    intx4 acc[4][8];
#pragma unroll
    for (int i = 0; i < 4; i++)
#pragma unroll
        for (int j = 0; j < 8; j++) acc[i][j] = (intx4){0, 0, 0, 0};

    // stage 256x128B i8 tile pair (32 KB each) with 512 threads: 4 issue
    // rounds of 8 KB per matrix. Linear LDS dest (tid*16); global source
    // column XOR-pre-swizzled with the read involution.
    auto stage = [&](int kt) {
#pragma unroll
        for (int i = 0; i < 4; ++i) {
            int off = i * 8192 + tid * 16;   // linear LDS byte offset, 0..32767
            int row = off >> 7;              // 128 B per row (256 rows)
            int colb = (off & 127) ^ ((row & 7) << 4);
            const unsigned char* srcA = Abase + (size_t)row * DD + kt * 128 + colb;
            const unsigned char* srcB = Bbase + (size_t)row * DD + kt * 128 + colb;
            __builtin_amdgcn_global_load_lds(
                (const __attribute__((address_space(1))) unsigned int*)srcA,
                (__attribute__((address_space(3))) unsigned int*)(&lds[0] + off),
                16, 0, 0);
            __builtin_amdgcn_global_load_lds(
                (const __attribute__((address_space(1))) unsigned int*)srcB,
                (__attribute__((address_space(3))) unsigned int*)(&lds[32768] + off),
                16, 0, 0);
        }
    };

    // i8 16x16x64 fragment for slice ks: lane (rl,g) holds k-bytes
    // ks*64 + g*16 .. +15 of its row -- one aligned ds_read_b128.
    auto ldfrag = [&](const unsigned char* base, int r, int ks) -> intx4 {
        int sw = (r & 7) << 4;
        return *(const intx4*)(base + r * 128 + ((ks * 64 + g * 16) ^ sw));
    };

    for (int kt = 0; kt < 8; ++kt) {
        stage(kt);
        __syncthreads();
#pragma unroll
        for (int ks = 0; ks < 2; ++ks) {
            intx4 af[4], bg[8];
#pragma unroll
            for (int f = 0; f < 4; ++f)
                af[f] = ldfrag(&lds[0], wr * 64 + f * 16 + rl, ks);
#pragma unroll
            for (int f = 0; f < 8; ++f)
                bg[f] = ldfrag(&lds[32768], wc * 128 + f * 16 + rl, ks);
#pragma unroll
            for (int fi = 0; fi < 4; ++fi)
#pragma unroll
                for (int fj = 0; fj < 8; ++fj)
                    acc[fi][fj] = __builtin_amdgcn_mfma_i32_16x16x64_i8(
                        af[fi], bg[fj], acc[fi][fj], 0, 0, 0);
        }
        __syncthreads();
    }

    // epilogue: strict-causal mask, row-max over this wave's 128-col half,
    // write partial to part[b][sj*2+wc][t]. sim = acc / 127^2.
    const float qs = 1.0f / 16129.0f;
    int t0g = ti * 256 + wr * 64;
    int s0g = sj * 256 + wc * 128;
#pragma unroll
    for (int fi = 0; fi < 4; ++fi) {
#pragma unroll
        for (int r = 0; r < 4; ++r) {
            int trow = t0g + fi * 16 + g * 4 + r;
            float m = -2.0f;
#pragma unroll
            for (int fj = 0; fj < 8; ++fj) {
                int scol = s0g + fj * 16 + rl;
                float v = (float)acc[fi][fj][r] * qs;
                m = fmaxf(m, (scol < trow) ? v : -2.0f);
            }
#pragma unroll
            for (int msk = 1; msk < 16; msk <<= 1) m = fmaxf(m, __shfl_xor(m, msk));
            if (rl == 0)
                part[(((size_t)b * 16 + sj * 2 + wc) << 11) + trow] = m;
        }
    }
}

// ------- kernel C: reduce partials + gate + recompute gelu(x), wave-per-row --
__global__ __launch_bounds__(256) void k_gate(
        const float* __restrict__ x, float* __restrict__ out,
        const float* __restrict__ ema_sim, const float* __restrict__ part,
        const float* __restrict__ log_tau,
        const float* __restrict__ log_blend,
        const float* __restrict__ logit_blend_seq) {
    int row = blockIdx.x * 4 + (threadIdx.x >> 6);
    int lane = threadIdx.x & 63;
    int b = row >> 11;
    int t = row & (TT - 1);

    int n = 2 * ((t >> 8) + 1);              // 2..16 column-halves present
    float m = (lane < n) ? part[(((size_t)b * 16 + lane) << 11) + t] : -2.0f;
#pragma unroll
    for (int msk = 1; msk < 64; msk <<= 1) m = fmaxf(m, __shfl_xor(m, msk));

    float tau = __expf(log_tau[0]);
    float alpha = 1.f / (1.f + __expf(-log_blend[0]));
    float wseq = 1.f / (1.f + __expf(-logit_blend_seq[0]));
    float es = ema_sim[row];
    float sq = (t > 0) ? m : es;
    float fam = wseq * sq + (1.f - wseq) * es;
    float gate = 1.f - alpha + alpha * __expf(-tau * fam);

    const float4* xr = reinterpret_cast<const float4*>(x + (size_t)row * DD);
    float4* orow = reinterpret_cast<float4*>(out + (size_t)row * DD);
#pragma unroll
    for (int j = 0; j < 4; ++j) {
        float4 v = xr[j * 64 + lane];
        float4 o;
        o.x = fast_gelu(v.x) * gate;
        o.y = fast_gelu(v.y) * gate;
        o.z = fast_gelu(v.z) * gate;
        o.w = fast_gelu(v.w) * gate;
        orow[j * 64 + lane] = o;
    }
}

extern "C" void kernel_launch(void* const* d_in, const int* in_sizes, int n_in,
                              void* d_out, int out_size, void* d_ws, size_t ws_size,
                              hipStream_t stream) {
    const float* x = (const float*)d_in[0];
    const float* ema = (const float*)d_in[1];
    // d_in[2] = logit_decay (unused by reference)
    const float* log_tau = (const float*)d_in[3];
    const float* log_blend = (const float*)d_in[4];
    const float* logit_bs = (const float*)d_in[5];
    float* out = (float*)d_out;

    char* ws = (char*)d_ws;
    float* ema_sim = (float*)(ws + (4 << 10));            // 64 KB
    float* part = (float*)(ws + (132 << 10));             // 1 MB (8*16*2048 f32)
    unsigned char* onrm8 = (unsigned char*)(ws + ((size_t)2304 << 10));  // 16 MB i8

    k_gelu_norm<<<NB * TT / 4, 256, 0, stream>>>(x, ema, (unsigned int*)onrm8, ema_sim);
    k_seqmax<<<NB * NPAIR2, 512, 0, stream>>>(onrm8, part);
    k_gate<<<NB * TT / 4, 256, 0, stream>>>(x, out, ema_sim, part,
                                            log_tau, log_blend, logit_bs);
}

// Round 20
// 72.831 us; speedup vs baseline: 1.1224x; 1.1224x over previous
//
#include <hip/hip_runtime.h>
#include <math.h>

#define NB 8
#define TT 2048
#define DD 1024
#define NTI 16            // 2048 / 128 t-tiles
#define NPAIR 136         // NTI*(NTI+1)/2

typedef __attribute__((ext_vector_type(4))) int intx4;
typedef __attribute__((ext_vector_type(4))) float floatx4;

__device__ inline float fast_gelu(float x) {
    // tanh(z) = 1 - 2/(exp(2z)+1); __expf -> v_exp_f32
    float z = 0.7978845608028654f * (x + 0.044715f * x * x * x);
    float e = __expf(2.0f * z);
    float th = 1.0f - 2.0f / (e + 1.0f);
    return 0.5f * x * (1.0f + th);
}

// ------- kernel A: gelu + row norm + ema dot -> int8 out_norm, ema_sim -------
__global__ __launch_bounds__(256) void k_gelu_norm(
        const float* __restrict__ x, const float* __restrict__ ema,
        unsigned int* __restrict__ onrm8, float* __restrict__ ema_sim) {
    int row = blockIdx.x * 4 + (threadIdx.x >> 6);
    int lane = threadIdx.x & 63;
    const float4* xr = reinterpret_cast<const float4*>(x + (size_t)row * DD);
    const float4* er = reinterpret_cast<const float4*>(ema);
    float g[16];
    float ss = 0.f, dt = 0.f, e2 = 0.f;
#pragma unroll
    for (int j = 0; j < 4; ++j) {
        float4 v = xr[j * 64 + lane];
        float4 e = er[j * 64 + lane];
        float vv[4] = {v.x, v.y, v.z, v.w};
        float ee[4] = {e.x, e.y, e.z, e.w};
        e2 += ee[0] * ee[0] + ee[1] * ee[1] + ee[2] * ee[2] + ee[3] * ee[3];
#pragma unroll
        for (int i = 0; i < 4; ++i) {
            float o = fast_gelu(vv[i]);
            g[j * 4 + i] = o;
            ss += o * o;
            dt += o * ee[i];
        }
    }
#pragma unroll
    for (int m = 1; m < 64; m <<= 1) {
        ss += __shfl_xor(ss, m);
        dt += __shfl_xor(dt, m);
        e2 += __shfl_xor(e2, m);
    }
    float inv = 1.0f / fmaxf(sqrtf(ss), 1e-12f);
    float einv = 1.0f / fmaxf(sqrtf(e2), 1e-12f);
    unsigned int* o8 = onrm8 + (size_t)row * (DD / 4);
#pragma unroll
    for (int j = 0; j < 4; ++j) {
        int q0 = (int)rintf(g[j * 4 + 0] * inv * 127.0f);
        int q1 = (int)rintf(g[j * 4 + 1] * inv * 127.0f);
        int q2 = (int)rintf(g[j * 4 + 2] * inv * 127.0f);
        int q3 = (int)rintf(g[j * 4 + 3] * inv * 127.0f);
        unsigned pk = (q0 & 255) | ((q1 & 255) << 8) | ((q2 & 255) << 16) |
                      ((unsigned)(q3 & 255) << 24);
        o8[j * 64 + lane] = pk;
    }
    if (lane == 0) ema_sim[row] = dt * inv * einv;
}

// -------- kernel B: causal max similarity, 128x128 int8 MFMA GEMM ------------
// Best measured configuration (R14, 72.9 us total). grid = NB*136 lower-tri
// 128x128 tile pairs, XCD-swizzled (batch per XCD; 2 MB i8 slice
// L2-resident). 4 waves, each 64x64 = 4x4 frags of mfma_i32_16x16x64_i8
// (proven 0-conflict ds_read_b128 pattern). BK=64 -> 16 K-steps,
// double-buffered 2x16KB LDS with counted s_waitcnt vmcnt(4): issue
// stage(kt+1), wait only own stage(kt) loads, raw barrier (all waves' chunks
// of buf done), compute, raw barrier (reads done -> restage safe).
// 64B rows use swizzle col ^= ((row>>1)&3)<<4 (<=2-way, free). Stage source
// pre-swizzled with the SAME involution (linear LDS dest).
__global__ __launch_bounds__(256) void k_seqmax(const unsigned char* __restrict__ onrm8,
                                                float* __restrict__ part) {
    __shared__ __align__(16) unsigned char lds[2][16384];  // per buf: A@0, B@8192

    int id = blockIdx.x;
    int nid = (id & 7) * NPAIR + (id >> 3);      // bijective: 1088 % 8 == 0
    int b = nid / NPAIR;
    int p = nid % NPAIR;
    int ti = (int)((sqrtf(8.0f * (float)p + 1.0f) - 1.0f) * 0.5f);
    while ((ti + 1) * (ti + 2) / 2 <= p) ++ti;
    while (ti * (ti + 1) / 2 > p) --ti;
    int sj = p - ti * (ti + 1) / 2;

    int lane = threadIdx.x & 63;
    int wave = threadIdx.x >> 6;
    int wr = wave >> 1, wc = wave & 1;
    int rl = lane & 15, g = lane >> 4;

    const unsigned char* Abase = onrm8 + (size_t)(b * TT + ti * 128) * DD;
    const unsigned char* Bbase = onrm8 + (size_t)(b * TT + sj * 128) * DD;

    intx4 acc[4][4];
#pragma unroll
    for (int i = 0; i < 4; i++)
#pragma unroll
        for (int j = 0; j < 4; j++) acc[i][j] = (intx4){0, 0, 0, 0};

    // stage 128x64B i8 tile pair (8 KB each) into lds[buf]: 8 chunks of 1 KB
    // per matrix, 2 per wave per matrix -> 4 gload_lds per wave per stage.
    auto stage = [&](int buf, int kt) {
#pragma unroll
        for (int i = 0; i < 2; ++i) {
            int c = wave * 2 + i;            // chunk 0..7
            int off = c * 1024 + lane * 16;  // linear LDS byte offset
            int row = off >> 6;              // 64 B per row
            int colb = (off & 63) ^ (((row >> 1) & 3) << 4);
            const unsigned char* srcA = Abase + (size_t)row * DD + kt * 64 + colb;
            const unsigned char* srcB = Bbase + (size_t)row * DD + kt * 64 + colb;
            __builtin_amdgcn_global_load_lds(
                (const __attribute__((address_space(1))) unsigned int*)srcA,
                (__attribute__((address_space(3))) unsigned int*)(&lds[buf][0] + c * 1024),
                16, 0, 0);
            __builtin_amdgcn_global_load_lds(
                (const __attribute__((address_space(1))) unsigned int*)srcB,
                (__attribute__((address_space(3))) unsigned int*)(&lds[buf][8192] + c * 1024),
                16, 0, 0);
        }
    };

    // i8 16x16x64 fragment: lane (rl,g) holds the 16 k-bytes g*16..+15 of its
    // row -- one aligned ds_read_b128, swizzle-consistent with stage.
    auto ldfrag = [&](const unsigned char* base, int r) -> intx4 {
        return *(const intx4*)(base + r * 64 + ((g * 16) ^ (((r >> 1) & 3) << 4)));
    };

    stage(0, 0);
    for (int kt = 0; kt < 16; ++kt) {
        int buf = kt & 1;
        if (kt + 1 < 16) {
            stage(buf ^ 1, kt + 1);
            // own stage(kt) 4 loads retired (oldest); the 4 just issued fly on
            asm volatile("s_waitcnt vmcnt(4)" ::: "memory");
        } else {
            asm volatile("s_waitcnt vmcnt(0)" ::: "memory");
        }
        __builtin_amdgcn_s_barrier();            // all waves' stage(kt) done
        __builtin_amdgcn_sched_barrier(0);
        const unsigned char* Ab = &lds[buf][0];
        const unsigned char* Bb = &lds[buf][8192];
        intx4 af[4], bg[4];
#pragma unroll
        for (int f = 0; f < 4; ++f) {
            af[f] = ldfrag(Ab, wr * 64 + f * 16 + rl);
            bg[f] = ldfrag(Bb, wc * 64 + f * 16 + rl);
        }
        __builtin_amdgcn_s_setprio(1);
#pragma unroll
        for (int fi = 0; fi < 4; ++fi)
#pragma unroll
            for (int fj = 0; fj < 4; ++fj)
                acc[fi][fj] = __builtin_amdgcn_mfma_i32_16x16x64_i8(
                    af[fi], bg[fj], acc[fi][fj], 0, 0, 0);
        __builtin_amdgcn_s_setprio(0);
        __builtin_amdgcn_sched_barrier(0);
        __builtin_amdgcn_s_barrier();            // reads of buf done -> restage ok
    }

    // epilogue: strict-causal mask, row-max over this wave's 64-col half,
    // write partial to part[b][sj*2+wc][t]. sim = acc / 127^2.
    const float qs = 1.0f / 16129.0f;
    int t0g = ti * 128 + wr * 64;
    int s0g = sj * 128 + wc * 64;
#pragma unroll
    for (int fi = 0; fi < 4; ++fi) {
#pragma unroll
        for (int r = 0; r < 4; ++r) {
            int trow = t0g + fi * 16 + g * 4 + r;
            float m = -2.0f;
#pragma unroll
            for (int fj = 0; fj < 4; ++fj) {
                int scol = s0g + fj * 16 + rl;
                float v = (float)acc[fi][fj][r] * qs;
                m = fmaxf(m, (scol < trow) ? v : -2.0f);
            }
#pragma unroll
            for (int msk = 1; msk < 16; msk <<= 1) m = fmaxf(m, __shfl_xor(m, msk));
            if (rl == 0)
                part[(((size_t)b * 32 + sj * 2 + wc) << 11) + trow] = m;
        }
    }
}

// ------- kernel C: reduce partials + gate + recompute gelu(x), wave-per-row --
__global__ __launch_bounds__(256) void k_gate(
        const float* __restrict__ x, float* __restrict__ out,
        const float* __restrict__ ema_sim, const float* __restrict__ part,
        const float* __restrict__ log_tau,
        const float* __restrict__ log_blend,
        const float* __restrict__ logit_blend_seq) {
    int row = blockIdx.x * 4 + (threadIdx.x >> 6);
    int lane = threadIdx.x & 63;
    int b = row >> 11;
    int t = row & (TT - 1);

    int n = 2 * ((t >> 7) + 1);              // 2..32 column-halves present
    float m = (lane < n) ? part[(((size_t)b * 32 + lane) << 11) + t] : -2.0f;
#pragma unroll
    for (int msk = 1; msk < 64; msk <<= 1) m = fmaxf(m, __shfl_xor(m, msk));

    float tau = __expf(log_tau[0]);
    float alpha = 1.f / (1.f + __expf(-log_blend[0]));
    float wseq = 1.f / (1.f + __expf(-logit_blend_seq[0]));
    float es = ema_sim[row];
    float sq = (t > 0) ? m : es;
    float fam = wseq * sq + (1.f - wseq) * es;
    float gate = 1.f - alpha + alpha * __expf(-tau * fam);

    const float4* xr = reinterpret_cast<const float4*>(x + (size_t)row * DD);
    float4* orow = reinterpret_cast<float4*>(out + (size_t)row * DD);
#pragma unroll
    for (int j = 0; j < 4; ++j) {
        float4 v = xr[j * 64 + lane];
        float4 o;
        o.x = fast_gelu(v.x) * gate;
        o.y = fast_gelu(v.y) * gate;
        o.z = fast_gelu(v.z) * gate;
        o.w = fast_gelu(v.w) * gate;
        orow[j * 64 + lane] = o;
    }
}

extern "C" void kernel_launch(void* const* d_in, const int* in_sizes, int n_in,
                              void* d_out, int out_size, void* d_ws, size_t ws_size,
                              hipStream_t stream) {
    const float* x = (const float*)d_in[0];
    const float* ema = (const float*)d_in[1];
    // d_in[2] = logit_decay (unused by reference)
    const float* log_tau = (const float*)d_in[3];
    const float* log_blend = (const float*)d_in[4];
    const float* logit_bs = (const float*)d_in[5];
    float* out = (float*)d_out;

    char* ws = (char*)d_ws;
    float* ema_sim = (float*)(ws + (4 << 10));            // 64 KB
    float* part = (float*)(ws + (132 << 10));             // 2 MB (8*32*2048 f32)
    unsigned char* onrm8 = (unsigned char*)(ws + ((size_t)2304 << 10));  // 16 MB i8

    k_gelu_norm<<<NB * TT / 4, 256, 0, stream>>>(x, ema, (unsigned int*)onrm8, ema_sim);
    k_seqmax<<<NB * NPAIR, 256, 0, stream>>>(onrm8, part);
    k_gate<<<NB * TT / 4, 256, 0, stream>>>(x, out, ema_sim, part,
                                            log_tau, log_blend, logit_bs);
}